// Round 16
// baseline (228.034 us; speedup 1.0000x reference)
//
#include <hip/hip_runtime.h>
#include <stdint.h>

#define BB 8
#define CC 16
#define HH 96
#define WW 96
#define HID 128
#define HW (HH*WW)            // 9216
#define CHW (CC*HW)           // 147456
#define NPIX (BB*HW)          // 73728
#define STEPS 16

typedef short s16x8 __attribute__((ext_vector_type(8)));   // 8 bf16 (4 VGPR)
typedef float f32x4 __attribute__((ext_vector_type(4)));   // MFMA acc

// ---------------- bf16 split helpers (RNE) ----------------
__device__ __host__ inline unsigned short bf16rne(float x) {
  union { float f; uint32_t u; } v; v.f = x;
  return (unsigned short)((v.u + 0x7fffu + ((v.u >> 16) & 1u)) >> 16);
}
__device__ __host__ inline float bf16f(unsigned short h) {
  union { uint32_t u; float f; } v; v.u = ((uint32_t)h) << 16; return v.f;
}

// ---------------- Threefry-2x32 (JAX-compatible, 20 rounds) ----------------
__host__ __device__ inline void threefry2x32(uint32_t k0, uint32_t k1,
                                             uint32_t x0, uint32_t x1,
                                             uint32_t& o0, uint32_t& o1) {
  const uint32_t ks2 = k0 ^ k1 ^ 0x1BD11BDAu;
  uint32_t v0 = x0 + k0, v1 = x1 + k1;
#define RL(v, r) (((v) << (r)) | ((v) >> (32 - (r))))
#define RND(r) { v0 += v1; v1 = RL(v1, r); v1 ^= v0; }
  RND(13) RND(15) RND(26) RND(6)   v0 += k1;  v1 += ks2 + 1u;
  RND(17) RND(29) RND(16) RND(24)  v0 += ks2; v1 += k0 + 2u;
  RND(13) RND(15) RND(26) RND(6)   v0 += k0;  v1 += k1 + 3u;
  RND(17) RND(29) RND(16) RND(24)  v0 += k1;  v1 += ks2 + 4u;
  RND(13) RND(15) RND(26) RND(6)   v0 += ks2; v1 += k0 + 5u;
#undef RND
#undef RL
  o0 = v0; o1 = v1;
}

// fire: partitionable threefry, bits = x0^x1 of cipher(key_i,(0,j)); <0.5 = top bit 0
__device__ inline float fire_val(uint32_t ka, uint32_t kb, uint32_t j) {
  uint32_t r0, r1;
  threefry2x32(ka, kb, 0u, j, r0, r1);
  return ((r0 ^ r1) & 0x80000000u) ? 0.0f : 1.0f;
}

// ---------------- prep: split + K-REORDERED + pre-permuted fragments --------
// New K order: wave q's 12 features at k=16q..16q+11 (k=16q+(cc*3+j),
// j:0=v11,1=gx,2=gy, old k_old=j*16+q+cc*4); pads 0; BIAS at k=15 (P[15]=1).
// Then fragment-order permutation (same as R13) so A-loads are coalesced.
__global__ void prep_w(const float* __restrict__ w1, const float* __restrict__ b1,
                       const float* __restrict__ w2,
                       unsigned short* __restrict__ w1fh, unsigned short* __restrict__ w1fl,
                       unsigned short* __restrict__ w2fh, unsigned short* __restrict__ w2fl) {
  int i = blockIdx.x * 256 + threadIdx.x;
  if (i < HID * 64) {
    int m = i >> 6, kn = i & 63;
    int q = kn >> 4, mm = kn & 15;
    float x;
    if (mm < 12) {
      int cc = mm / 3, j = mm - cc * 3;
      x = w1[m * 48 + j * 16 + q + cc * 4];
    } else if (kn == 15) {
      x = b1[m];
    } else {
      x = 0.f;
    }
    int mq = m >> 5, mp = (m >> 4) & 1, lm = m & 15;
    int kg = kn >> 3, e = kn & 7, ks = kg >> 2, lg = kg & 3;
    int dst = ((((mq * 2 + mp) * 2 + ks) * 64) + lg * 16 + lm) * 8 + e;
    unsigned short hb = bf16rne(x);
    w1fh[dst] = hb; w1fl[dst] = bf16rne(x - bf16f(hb));
  } else if (i < HID * 64 + CC * HID) {
    int j = i - HID * 64;
    int m = j >> 7, k = j & 127;
    float x = w2[m * 128 + k];
    int kg = k >> 3, e = k & 7, ks = kg >> 2, lg = kg & 3;
    int dst = ((ks * 64) + lg * 16 + m) * 8 + e;
    unsigned short hb = bf16rne(x);
    w2fh[dst] = hb; w2fl[dst] = bf16rne(x - bf16f(hb));
  }
}

// ---------------- Fused step kernel (MFMA; 16x8 tile, 2 GEMM halves) --------
// R15 numerics (3-pass GEMM1, 3-pass GEMM2 incl y_lo). Structural:
//  (1) 128-px tile: staging/life/xt/prelife/fire once per 128 px; GEMM as two
//      64-px halves reusing pf/yf. Grid 576 = 8 x 72, single resident round.
//  (2) pf writes now 4x ds_write_b128 (conflict-free contiguous 1KB/wave)
//      via the K-reorder, replacing 24x 8-way-conflicted b16 scatters.
__global__ __launch_bounds__(256, 3) void ca_fused(
    const float* __restrict__ src, const float* __restrict__ plprev,
    const unsigned short* __restrict__ w1fh, const unsigned short* __restrict__ w1fl,
    const unsigned short* __restrict__ w2fh, const unsigned short* __restrict__ w2fl,
    const float* __restrict__ b2,
    float* __restrict__ rawout, float* __restrict__ plout,
    uint32_t ka, uint32_t kb, int apply_life)
{
  __shared__ __align__(16) unsigned char smem[46592];
  unsigned char* pfh   = smem;                   // 8192
  unsigned char* pfl   = smem + 8192;            // 8192
  unsigned char* yfh   = smem;                   // 16384 (overlays pf per half)
  unsigned char* yfl   = smem + 16384;           // 16384
  float* xt            = (float*)(smem + 32768); // [16][180] = 11520 B (persists)
  float* raw3          = (float*)(smem + 44288); // 240*4 = 960 B
  float* life_l        = (float*)(smem + 45248); // 180*4 = 720 B
  float* fire_lds      = (float*)(smem + 45968); // 128*4 = 512 B

  const int tid  = threadIdx.x;
  const int lane = tid & 63;
  const int q    = __builtin_amdgcn_readfirstlane(tid >> 6);
  const int b    = blockIdx.x & 7;           // batch == XCD slot
  const int t    = blockIdx.x >> 3;          // tile 0..71
  const int h0   = (t / 6) * 8, w0 = (t % 6) * 16;   // 16-wide, 8-tall tile
  const int lm   = lane & 15, lg = lane >> 4;

  // ---- A1-fragments: coalesced loads from pre-permuted arrays (once/block)
  s16x8 a1h[2][2], a1l[2][2];
#pragma unroll
  for (int mp = 0; mp < 2; ++mp)
#pragma unroll
    for (int ks = 0; ks < 2; ++ks) {
      const int off = ((((q * 2 + mp) * 2 + ks) * 64) + lane) * 8;
      a1h[mp][ks] = *reinterpret_cast<const s16x8*>(w1fh + off);
      a1l[mp][ks] = *reinterpret_cast<const s16x8*>(w1fl + off);
    }
  const f32x4 b2v = reinterpret_cast<const f32x4*>(b2)[lg];

  // ---- issue ALL staging loads now (latency hidden by barrier chain)
  float r3v = 0.f;
  if (apply_life && tid < 240) {              // raw ch3, 12x20
    const int r = tid / 20, c = tid - r * 20;
    const int hh = h0 - 2 + r, ww = w0 - 2 + c;
    if (hh >= 0 && hh < HH && ww >= 0 && ww < WW)
      r3v = src[b * CHW + 3 * HW + hh * WW + ww];
  }
  float plv = 0.f;
  if (apply_life && tid < 180) {              // prelife, 10x18
    const int r = tid / 18, c = tid - r * 18;
    const int hh = h0 - 1 + r, ww = w0 - 1 + c;
    if (hh >= 0 && hh < HH && ww >= 0 && ww < WW)
      plv = plprev[b * HW + hh * WW + ww];
  }
  float xreg[12];                             // x tile 16ch x 10x18 = 2880
#pragma unroll
  for (int ii = 0; ii < 12; ++ii) {
    xreg[ii] = 0.f;
    const int idx = tid + ii * 256;
    if (idx < CC * 180) {
      const int ch = idx / 180, rc = idx - ch * 180;
      const int r = rc / 18, c = rc - r * 18;
      const int hh = h0 - 1 + r, ww = w0 - 1 + c;
      if (hh >= 0 && hh < HH && ww >= 0 && ww < WW)
        xreg[ii] = src[b * CHW + ch * HW + hh * WW + ww];
    }
  }

  // ---- life chain
  if (apply_life) {
    if (tid < 240) raw3[tid] = r3v;
    __syncthreads();
    if (tid < 180) {
      const int r = tid / 18, c = tid - r * 18;
      float m = fmaxf(fmaxf(raw3[r * 20 + c],        raw3[r * 20 + c + 1]),
                      fmaxf(raw3[r * 20 + c + 2],    raw3[(r + 1) * 20 + c]));
      m = fmaxf(m, fmaxf(raw3[(r + 1) * 20 + c + 1], raw3[(r + 1) * 20 + c + 2]));
      m = fmaxf(m, fmaxf(raw3[(r + 2) * 20 + c],     raw3[(r + 2) * 20 + c + 1]));
      m = fmaxf(m, raw3[(r + 2) * 20 + c + 2]);
      life_l[tid] = ((m > 0.1f) && (plv > 0.1f)) ? 1.f : 0.f;
    }
    __syncthreads();
  }

  // ---- build x tile from prefetched registers
#pragma unroll
  for (int ii = 0; ii < 12; ++ii) {
    const int idx = tid + ii * 256;
    if (idx < CC * 180) {
      const int ch = idx / 180, rc = idx - ch * 180;
      float v = xreg[ii];
      if (apply_life) {
        v *= life_l[rc];
        v = fminf(fmaxf(v, -10.f), 10.f);
      }
      xt[ch * 180 + rc] = v;
    }
  }
  __syncthreads();

  // ---- prelife (tid<128) + fire (tid>=128) for the 128 interior px
  if (tid < 128) {
    const int py = tid >> 4, pxx = tid & 15;
    const float* x3 = xt + 3 * 180;
    const int base = py * 18 + pxx;
    float m = fmaxf(fmaxf(x3[base],      x3[base + 1]),
                    fmaxf(x3[base + 2],  x3[base + 18]));
    m = fmaxf(m, fmaxf(x3[base + 19], x3[base + 20]));
    m = fmaxf(m, fmaxf(x3[base + 36], x3[base + 37]));
    m = fmaxf(m, x3[base + 38]);
    plout[b * HW + (h0 + py) * WW + w0 + pxx] = m;
  } else {
    const int i = tid - 128;
    const int py = i >> 4, pxx = i & 15;
    fire_lds[i] = fire_val(ka, kb, (uint32_t)(b * HW + (h0 + py) * WW + w0 + pxx));
  }

  // ================= two 64-px GEMM halves =================
#pragma unroll 1
  for (int hf = 0; hf < 2; ++hf) {
    // ---- perception -> K-reordered frag units: 4x conflict-free b128/lane
    {
      const int pp  = hf * 64 + lane;             // pixel in 16x8 tile
      const int ctr = ((pp >> 4) + 1) * 18 + (pp & 15) + 1;
      float fv[12];
#pragma unroll
      for (int cc = 0; cc < 4; ++cc) {
        const int c = q + cc * 4;                 // wave-uniform channel
        const float* xc = xt + c * 180;
        const float v00 = xc[ctr - 19], v01 = xc[ctr - 18], v02 = xc[ctr - 17];
        const float v10 = xc[ctr - 1],  v11 = xc[ctr],      v12 = xc[ctr + 1];
        const float v20 = xc[ctr + 17], v21 = xc[ctr + 18], v22 = xc[ctr + 19];
        fv[cc * 3 + 0] = v11;
        fv[cc * 3 + 1] = ((v02 - v00) + 2.f * (v12 - v10) + (v22 - v20)) * 0.125f;
        fv[cc * 3 + 2] = ((v20 - v00) + 2.f * (v21 - v01) + (v22 - v02)) * 0.125f;
      }
      s16x8 ph[2], pl[2];
#pragma unroll
      for (int u = 0; u < 2; ++u)
#pragma unroll
        for (int e = 0; e < 8; ++e) {
          const int m = u * 8 + e;
          if (m < 12) {
            const unsigned short hb = bf16rne(fv[m]);
            ph[u][e] = (short)hb;
            pl[u][e] = (short)bf16rne(fv[m] - bf16f(hb));
          } else if (m == 15) {
            ph[u][e] = (short)((q == 0) ? 0x3F80 : 0);  // bias slot: P=1.0
            pl[u][e] = 0;
          } else {
            ph[u][e] = 0; pl[u][e] = 0;
          }
        }
#pragma unroll
      for (int u = 0; u < 2; ++u) {
        const int kgw = 2 * q + u;
        const int un = kgw * 64 + ((lane + kgw) & 63);
        *reinterpret_cast<s16x8*>(pfh + un * 16) = ph[u];
        *reinterpret_cast<s16x8*>(pfl + un * 16) = pl[u];
      }
    }
    __syncthreads();               // pf ready

    // ---- epilogue center values for this half -> registers
    const int opx = q * 16 + lm;               // pixel-in-half
    const int pp2 = hf * 64 + opx;
    const int opy = pp2 >> 4, owx = pp2 & 15;
    const int octr = (1 + opy) * 18 + (1 + owx);
    float xcv[4];
#pragma unroll
    for (int r = 0; r < 4; ++r) xcv[r] = xt[(lg * 4 + r) * 180 + octr];

    // ---- GEMM1: acc += W1*P, 3-pass split
    f32x4 acc[2][4];
#pragma unroll
    for (int mp = 0; mp < 2; ++mp)
#pragma unroll
      for (int nt = 0; nt < 4; ++nt) acc[mp][nt] = (f32x4){0.f, 0.f, 0.f, 0.f};

#pragma unroll
    for (int nt = 0; nt < 4; ++nt) {
#pragma unroll
      for (int ks = 0; ks < 2; ++ks) {
        const int kg = ks * 4 + lg;
        const int un = kg * 64 + ((nt * 16 + lm + kg) & 63);
        const s16x8 bh = *reinterpret_cast<const s16x8*>(pfh + un * 16);
        const s16x8 bl = *reinterpret_cast<const s16x8*>(pfl + un * 16);
#pragma unroll
        for (int mp = 0; mp < 2; ++mp) {
          acc[mp][nt] = __builtin_amdgcn_mfma_f32_16x16x32_bf16(a1l[mp][ks], bh, acc[mp][nt], 0, 0, 0);
          acc[mp][nt] = __builtin_amdgcn_mfma_f32_16x16x32_bf16(a1h[mp][ks], bl, acc[mp][nt], 0, 0, 0);
          acc[mp][nt] = __builtin_amdgcn_mfma_f32_16x16x32_bf16(a1h[mp][ks], bh, acc[mp][nt], 0, 0, 0);
        }
      }
    }
    __syncthreads();               // pf reads done -> overlay yfh

    // ---- Y = relu(acc) split to bf16 hi/lo frag units
#pragma unroll
    for (int mp = 0; mp < 2; ++mp) {
      const int k0 = (2 * q + mp) * 16 + lg * 4;
      const int kg = k0 >> 3, e0 = k0 & 7;
#pragma unroll
      for (int nt = 0; nt < 4; ++nt) {
        const int un = kg * 64 + ((nt * 16 + lm + kg) & 63);
        unsigned int hwv[2], lwv[2];
#pragma unroll
        for (int pr = 0; pr < 2; ++pr) {
          const float ya = fmaxf(acc[mp][nt][2 * pr], 0.f);
          const float yb = fmaxf(acc[mp][nt][2 * pr + 1], 0.f);
          const unsigned short ha = bf16rne(ya), hb2 = bf16rne(yb);
          const unsigned short la = bf16rne(ya - bf16f(ha));
          const unsigned short lb = bf16rne(yb - bf16f(hb2));
          hwv[pr] = (unsigned int)ha | ((unsigned int)hb2 << 16);
          lwv[pr] = (unsigned int)la | ((unsigned int)lb << 16);
        }
        *reinterpret_cast<uint2*>(yfh + un * 16 + e0 * 2) = make_uint2(hwv[0], hwv[1]);
        *reinterpret_cast<uint2*>(yfl + un * 16 + e0 * 2) = make_uint2(lwv[0], lwv[1]);
      }
    }
    __syncthreads();               // yf ready

    // ---- GEMM2: U[16][16px], 3-pass split over K=128; a2 frags loaded here
    f32x4 acc2 = (f32x4){0.f, 0.f, 0.f, 0.f};
#pragma unroll
    for (int ks = 0; ks < 4; ++ks) {
      const int woff = ((ks * 64) + lane) * 8;
      const s16x8 a2l = *reinterpret_cast<const s16x8*>(w2fl + woff);  // L2-hot
      const s16x8 a2h = *reinterpret_cast<const s16x8*>(w2fh + woff);
      const int kg = ks * 4 + lg;
      const int un = kg * 64 + ((q * 16 + lm + kg) & 63);
      const s16x8 bh = *reinterpret_cast<const s16x8*>(yfh + un * 16);
      const s16x8 bl = *reinterpret_cast<const s16x8*>(yfl + un * 16);
      acc2 = __builtin_amdgcn_mfma_f32_16x16x32_bf16(a2l, bh, acc2, 0, 0, 0);
      acc2 = __builtin_amdgcn_mfma_f32_16x16x32_bf16(a2h, bl, acc2, 0, 0, 0);
      acc2 = __builtin_amdgcn_mfma_f32_16x16x32_bf16(a2h, bh, acc2, 0, 0, 0);
    }

    // ---- epilogue: raw = x + (U + b2) * fire
    const float fire = fire_lds[pp2];
    const int gb = b * CHW + (h0 + opy) * WW + (w0 + owx);
#pragma unroll
    for (int r = 0; r < 4; ++r) {
      const int c = lg * 4 + r;
      rawout[gb + c * HW] = xcv[r] + (acc2[r] + b2v[r]) * fire;
    }
    if (hf == 0) __syncthreads();  // yf reads done -> half B may rewrite pf
  }
}

// ---------------- Final kernel: life mask + clip -> output -----------------
__global__ __launch_bounds__(256) void ca_life(
    const float* __restrict__ prelife, const float* __restrict__ raw,
    float* __restrict__ xnext)
{
  const int lane = threadIdx.x & 63;
  const int g    = threadIdx.x >> 6;
  const int b    = blockIdx.x & 7;
  const int seg  = blockIdx.x >> 3;
  const int rem  = seg * 64 + lane;
  const int h = rem / WW;
  const int w = rem - h * WW;
  const int P = b * HW + rem;
  const bool hm = (h > 0), hp = (h < HH - 1), wm = (w > 0), wp = (w < WW - 1);

  float m2;
  {
    const float* xr = raw + b * CHW + 3 * HW + h * WW + w;
    m2 = xr[0];
    if (hm) {
      m2 = fmaxf(m2, xr[-WW]);
      if (wm) m2 = fmaxf(m2, xr[-WW - 1]);
      if (wp) m2 = fmaxf(m2, xr[-WW + 1]);
    }
    if (wm) m2 = fmaxf(m2, xr[-1]);
    if (wp) m2 = fmaxf(m2, xr[ 1]);
    if (hp) {
      m2 = fmaxf(m2, xr[WW]);
      if (wm) m2 = fmaxf(m2, xr[WW - 1]);
      if (wp) m2 = fmaxf(m2, xr[WW + 1]);
    }
  }
  const float life = ((prelife[P] > 0.1f) && (m2 > 0.1f)) ? 1.f : 0.f;

  const int base = b * CHW + h * WW + w;
#pragma unroll
  for (int cc = 0; cc < 4; ++cc) {
    const int c = g + cc * 4;
    float v = raw[base + c * HW] * life;
    v = fminf(fmaxf(v, -10.f), 10.f);
    xnext[base + c * HW] = v;
  }
}

// ---------------- launcher ----------------
extern "C" void kernel_launch(void* const* d_in, const int* in_sizes, int n_in,
                              void* d_out, int out_size, void* d_ws, size_t ws_size,
                              hipStream_t stream) {
  const float* x  = (const float*)d_in[0];
  const float* w1 = (const float*)d_in[1];
  const float* b1 = (const float*)d_in[2];
  const float* w2 = (const float*)d_in[3];
  const float* b2 = (const float*)d_in[4];
  float* out = (float*)d_out;

  char* ws = (char*)d_ws;
  const size_t BUF = (size_t)NPIX * CC * sizeof(float);   // 4,718,592 B
  float* rawA = (float*)(ws);
  float* rawB = (float*)(ws + BUF);
  float* plA  = (float*)(ws + 2 * BUF);
  float* plB  = (float*)(ws + 2 * BUF + (size_t)NPIX * 4);
  unsigned short* w1fh = (unsigned short*)(ws + 2 * BUF + 2 * (size_t)NPIX * 4);
  unsigned short* w1fl = w1fh + HID * 64;
  unsigned short* w2fh = w1fl + HID * 64;
  unsigned short* w2fl = w2fh + CC * HID;

  hipLaunchKernelGGL(prep_w, dim3(40), dim3(256), 0, stream,
                     w1, b1, w2, w1fh, w1fl, w2fh, w2fl);

  for (int i = 0; i < STEPS; ++i) {
    uint32_t ka, kb;
    threefry2x32(0u, 42u, 0u, (uint32_t)i, ka, kb);       // fold_in(key(42), i)
    const float* src = (i == 0) ? x : ((i & 1) ? rawA : rawB);
    const float* plp = (i & 1) ? plA : plB;
    float* ro        = (i & 1) ? rawB : rawA;             // raw_i
    float* po        = (i & 1) ? plB : plA;               // prelife_i
    hipLaunchKernelGGL(ca_fused, dim3(8 * 72), dim3(256), 0, stream,
                       src, plp, w1fh, w1fl, w2fh, w2fl, b2, ro, po,
                       ka, kb, (i == 0) ? 0 : 1);
  }
  // raw_15 / prelife_15 are in rawB / plB (15 is odd)
  hipLaunchKernelGGL(ca_life, dim3(NPIX / 64), dim3(256), 0, stream,
                     plB, rawB, out);
  (void)in_sizes; (void)n_in; (void)out_size; (void)ws_size;
}